// Round 1
// baseline (96.400 us; speedup 1.0000x reference)
//
#include <hip/hip_runtime.h>

constexpr int DIM = 4096;

__device__ __forceinline__ float4 f4add(float4 a, float4 b) {
    return make_float4(a.x + b.x, a.y + b.y, a.z + b.z, a.w + b.w);
}
__device__ __forceinline__ float4 f4sub(float4 a, float4 b) {
    return make_float4(a.x - b.x, a.y - b.y, a.z - b.z, a.w - b.w);
}

// FWHT over the 2 low bits (c) inside one float4: order [x,y,z,w] = c 0..3
__device__ __forceinline__ float4 fwht4_inner(float4 v) {
    float a = v.x + v.y, b = v.x - v.y;
    float c = v.z + v.w, d = v.z - v.w;
    return make_float4(a + c, b + d, a - c, b - d);
}

// In-register 16-point FWHT (4 stages), reference sign convention:
// bit=0 lane gets a+b, bit=1 lane gets a-b.
__device__ __forceinline__ void fwht16(float* v) {
#pragma unroll
    for (int s = 1; s < 16; s <<= 1) {
#pragma unroll
        for (int m = 0; m < 16; ++m) {
            if (!(m & s)) {
                float a = v[m], b = v[m ^ s];
                v[m]     = a + b;
                v[m ^ s] = a - b;
            }
        }
    }
}

// LDS physical address swizzle (involution, bijective):
//   phi(i) = i ^ (((i>>10)&3)<<2) ^ (((i>>6)&3)<<4)
// Folds bits {10,11} into {2,3} and bits {6,7} into {4,5} so every
// access pattern below is <=2 lanes/bank (free on wave64).

__global__ __launch_bounds__(256, 4) void fwht_kernel(const float* __restrict__ x,
                                                      float* __restrict__ out) {
    __shared__ float lds0[DIM];
    __shared__ float lds1[DIM];

    const int t = threadIdx.x;
    const size_t base = (size_t)blockIdx.x * DIM;

    // ---- coalesced load: f[j] = X4[j*256 + t]; element i = j*1024 + t*4 + c
    const float4* X4 = reinterpret_cast<const float4*>(x + base);
    float4 f0 = X4[t];
    float4 f1 = X4[256 + t];
    float4 f2 = X4[512 + t];
    float4 f3 = X4[768 + t];

    // ---- R1: FWHT over bits {0,1} (c, intra-float4) and {10,11} (j)
    f0 = fwht4_inner(f0);
    f1 = fwht4_inner(f1);
    f2 = fwht4_inner(f2);
    f3 = fwht4_inner(f3);
    {
        float4 s0 = f4add(f0, f1), d0 = f4sub(f0, f1);
        float4 s1 = f4add(f2, f3), d1 = f4sub(f2, f3);
        f0 = f4add(s0, s1);  // j=0
        f1 = f4add(d0, d1);  // j=1
        f2 = f4sub(s0, s1);  // j=2
        f3 = f4sub(d0, d1);  // j=3
    }

    // ---- T1-write: i = j*1024 + t*4 + c, stored at phi(i), as float4 chunks.
    // dword base = (t<<2) ^ (t_hi_low2 << 4); per-j chunk gets (j<<10) | base, ^ (j<<2)
    {
        const int dbase = (t << 2) ^ (((t >> 4) & 3) << 4);
        float4* L = reinterpret_cast<float4*>(lds0);
        L[(((0 << 10) | dbase) ^ (0 << 2)) >> 2] = f0;
        L[(((1 << 10) | dbase) ^ (1 << 2)) >> 2] = f1;
        L[(((2 << 10) | dbase) ^ (2 << 2)) >> 2] = f2;
        L[(((3 << 10) | dbase) ^ (3 << 2)) >> 2] = f3;
    }
    __syncthreads();

    // ---- T1-read: thread t' = (th<<4)|(j<<2)|c holds m=0..15 (i bits 2..5)
    //      i = j*1024 + th*64 + m*4 + c
    float w[16];
    {
        const int c  = t & 3;
        const int j  = (t >> 2) & 3;
        const int th = t >> 4;
        const int b  = (j << 10) | (th << 6) | c;
        const int xo = (j << 2) ^ ((th & 3) << 4);
#pragma unroll
        for (int m = 0; m < 16; ++m)
            w[m] = lds0[b | ((m << 2) ^ xo)];
    }

    // ---- R2: FWHT over bits {2,3,4,5}
    fwht16(w);

    // ---- T2-write (same addresses, second buffer)
    {
        const int c  = t & 3;
        const int j  = (t >> 2) & 3;
        const int th = t >> 4;
        const int b  = (j << 10) | (th << 6) | c;
        const int xo = (j << 2) ^ ((th & 3) << 4);
#pragma unroll
        for (int m = 0; m < 16; ++m)
            lds1[b | ((m << 2) ^ xo)] = w[m];
    }
    __syncthreads();

    // ---- T2-read: thread t'' = (j2<<6)|(tl<<2)|c2 holds n=0..15 (i bits 6..9)
    //      i = j2*1024 + n*64 + tl*4 + c2
    float z[16];
    const int c2 = t & 3;
    const int tl = (t >> 2) & 15;
    const int j2 = t >> 6;
    {
        const int b2 = (j2 << 10) | (tl << 2) | c2;
        const int xb = b2 ^ (j2 << 2);
#pragma unroll
        for (int n = 0; n < 16; ++n)
            z[n] = lds1[(xb ^ ((n & 3) << 4)) | (n << 6)];
    }

    // ---- R3: FWHT over bits {6,7,8,9}, scale, coalesced store
    fwht16(z);

    float* O = out + base;
    const int ob = (j2 << 10) | (tl << 2) | c2;
#pragma unroll
    for (int n = 0; n < 16; ++n)
        O[ob | (n << 6)] = z[n] * 0.015625f;  // 1/64
}

extern "C" void kernel_launch(void* const* d_in, const int* in_sizes, int n_in,
                              void* d_out, int out_size, void* d_ws, size_t ws_size,
                              hipStream_t stream) {
    const float* x = (const float*)d_in[0];
    float* out = (float*)d_out;
    const int rows = in_sizes[0] / DIM;  // 16384
    fwht_kernel<<<rows, 256, 0, stream>>>(x, out);
}

// Round 2
// 85.959 us; speedup vs baseline: 1.1215x; 1.1215x over previous
//
#include <hip/hip_runtime.h>

constexpr int DIM = 4096;
using f32x4 = __attribute__((ext_vector_type(4))) float;

// FWHT over the 2 low bits (c) inside one float4: slots [0..3] = c 0..3
__device__ __forceinline__ f32x4 fwht4_inner(f32x4 v) {
    float a = v.x + v.y, b = v.x - v.y;
    float c = v.z + v.w, d = v.z - v.w;
    f32x4 r;
    r.x = a + c; r.y = b + d; r.z = a - c; r.w = b - d;
    return r;
}

// In-register 16-point FWHT (4 stages): bit=0 lane gets a+b, bit=1 gets a-b.
__device__ __forceinline__ void fwht16(float* v) {
#pragma unroll
    for (int s = 1; s < 16; s <<= 1) {
#pragma unroll
        for (int m = 0; m < 16; ++m) {
            if (!(m & s)) {
                float a = v[m], b = v[m ^ s];
                v[m]     = a + b;
                v[m ^ s] = a - b;
            }
        }
    }
}

// Bit plan (i = element index, 12 bits):
//   load:  i = c + 4t + 1024j   (t = w*64 + l)
//          c = i{0,1}, l = i{2..7}, w = i{8,9}, j = i{10,11}
//   R1: bits {0,1,10,11} in registers
//   T1: WAVE-LOCAL transpose (bits {2..5} are lane bits) -> no barrier
//   R2: bits {2..5}
//   T2: block-wide transpose (needs bits {8,9} = wave bits) -> one barrier
//   R3: bits {6..9}, scale, coalesced store
//
// T1 region layout (1024 floats per wave): idx = i{0,1} | (i{2..7}<<2) | (i{10,11}<<8)
//   swizzle s(a) = a ^ ((a>>6 & 3)<<2) ^ ((a>>8 & 1)<<4)   (involution)
// T2 layout (4096 floats, natural a = i):
//   swizzle s2(a) = a ^ ((a>>6 & 3)<<2) ^ ((a>>10 & 1)<<4) (involution)
// All four LDS access patterns verified <=2 lanes/bank (free on wave64).

__global__ __launch_bounds__(256, 4) void fwht_kernel(const float* __restrict__ x,
                                                      float* __restrict__ out) {
    __shared__ f32x4 lds0v[DIM / 4];  // T1: 4 wave-private 256-float4 regions
    __shared__ float lds1[DIM];       // T2: block-wide
    float* lds0 = reinterpret_cast<float*>(lds0v);

    const int t = threadIdx.x;
    const int l = t & 63;
    const int w = t >> 6;
    const size_t base = (size_t)blockIdx.x * DIM;

    // ---- coalesced nt load: f[j] = X4[j*256 + t]
    const f32x4* X4 = reinterpret_cast<const f32x4*>(x + base);
    f32x4 f0 = __builtin_nontemporal_load(X4 + t);
    f32x4 f1 = __builtin_nontemporal_load(X4 + 256 + t);
    f32x4 f2 = __builtin_nontemporal_load(X4 + 512 + t);
    f32x4 f3 = __builtin_nontemporal_load(X4 + 768 + t);

    // ---- R1: FWHT over bits {0,1} (c) and {10,11} (j)
    f0 = fwht4_inner(f0);
    f1 = fwht4_inner(f1);
    f2 = fwht4_inner(f2);
    f3 = fwht4_inner(f3);
    {
        f32x4 s0 = f0 + f1, d0 = f0 - f1;
        f32x4 s1 = f2 + f3, d1 = f2 - f3;
        f0 = s0 + s1;  // j=0
        f1 = d0 + d1;  // j=1
        f2 = s0 - s1;  // j=2
        f3 = d0 - d1;  // j=3
    }

    // ---- T1-write (wave-local): dword idx = (l<<2) | (j<<8), swizzled
    {
        f32x4* R = lds0v + (w << 8);
        const int b0 = (l << 2) ^ (((l >> 4) & 3) << 2);  // ^ ((idx>>6&3)<<2)
        R[b0 >> 2]                  = f0;  // j=0
        R[((b0 ^ 16) | 256) >> 2]   = f1;  // j=1: ^((j&1)<<4)
        R[(b0 | 512) >> 2]          = f2;  // j=2
        R[((b0 ^ 16) | 768) >> 2]   = f3;  // j=3
    }
    asm volatile("s_waitcnt lgkmcnt(0)" ::: "memory");

    // ---- T1-read (wave-local): thread holds m = i{2..5};
    //      fixed c1 = i{0,1}, h1 = i{6,7}, j1 = i{10,11}
    float wv[16];
    const int c1 = l & 3;
    const int h1 = (l >> 2) & 3;
    const int j1 = l >> 4;
    {
        float* Rf = lds0 + (w << 10);
        const int rb = (c1 | (h1 << 6) | (j1 << 8)) ^ (h1 << 2) ^ ((j1 & 1) << 4);
#pragma unroll
        for (int m = 0; m < 16; ++m)
            wv[m] = Rf[rb ^ (m << 2)];
    }

    // ---- R2: FWHT over bits {2..5}
    fwht16(wv);

    // ---- T2-write (block-wide): a = i natural, swizzled with s2
    {
        const int tb = (c1 | (h1 << 6) | (w << 8) | (j1 << 10)) ^ (h1 << 2) ^ ((j1 & 1) << 4);
#pragma unroll
        for (int m = 0; m < 16; ++m)
            lds1[tb ^ (m << 2)] = wv[m];
    }
    __syncthreads();

    // ---- T2-read: thread holds n = i{6..9}; fixed i{0..5} = l, i{10,11} = w
    float z[16];
    {
        const int qb = (l | (w << 10)) ^ ((w & 1) << 4);
#pragma unroll
        for (int n = 0; n < 16; ++n)
            z[n] = lds1[qb ^ (n << 6) ^ ((n & 3) << 2)];
    }

    // ---- R3: FWHT over bits {6..9}, scale, coalesced nt store
    fwht16(z);

    float* O = out + base + (w << 10) + l;
#pragma unroll
    for (int n = 0; n < 16; ++n)
        __builtin_nontemporal_store(z[n] * 0.015625f, O + (n << 6));
}

extern "C" void kernel_launch(void* const* d_in, const int* in_sizes, int n_in,
                              void* d_out, int out_size, void* d_ws, size_t ws_size,
                              hipStream_t stream) {
    const float* x = (const float*)d_in[0];
    float* out = (float*)d_out;
    const int rows = in_sizes[0] / DIM;  // 16384
    fwht_kernel<<<rows, 256, 0, stream>>>(x, out);
}